// Round 1
// baseline (211.039 us; speedup 1.0000x reference)
//
#include <hip/hip_runtime.h>

namespace {
constexpr int LROW   = 8192;
constexpr int KWIN   = 25;
constexpr int HALF   = (KWIN - 1) / 2;    // 12
constexpr int PERIOD = 24;
constexpr int NOCC   = 342;               // (L + 16) / 24 occurrences per phase
constexpr int NTHR   = 256;
constexpr int GRP    = LROW / (4 * NTHR); // 8 float4-groups per thread
}

__device__ __forceinline__ void ce(float& x, float& y) {
    float lo = fminf(x, y), hi = fmaxf(x, y);
    x = lo; y = hi;
}

// exact median of 5 via 9-CE sorting network (Knuth-equivalent, verified)
__device__ __forceinline__ float median5(float a, float b, float c, float d, float e) {
    ce(a, b); ce(d, e); ce(c, e); ce(c, d); ce(a, d); ce(a, c);
    ce(b, e); ce(b, d); ce(b, c);
    return c;
}

__global__ __launch_bounds__(NTHR, 4) void decomp_kernel(
    const float* __restrict__ x,
    float* __restrict__ out_res,
    float* __restrict__ out_trend,
    float* __restrict__ out_seas)
{
    // padded row: buf[0..11]=front pad, buf[12..8203]=x row, buf[8204..8215]=end pad
    __shared__ __align__(16) float buf[HALF + LROW + HALF];
    __shared__ float part[240];
    __shared__ float seasonal[PERIOD];
    __shared__ float med_front, med_end;

    float* xs = buf + HALF;
    const int t = threadIdx.x;
    const size_t base = (size_t)blockIdx.x * LROW;
    const float* xr = x + base;

    // ---- stage row -> LDS (float4, coalesced global, lane-consecutive LDS) ----
    #pragma unroll
    for (int j = 0; j < GRP; ++j) {
        int g = 4 * (t + NTHR * j);
        *reinterpret_cast<float4*>(xs + g) =
            *reinterpret_cast<const float4*>(xr + g);
    }
    __syncthreads();

    // ---- median-of-5 pads ----
    if (t == 0) med_front = median5(xs[0], xs[1], xs[2], xs[3], xs[4]);
    if (t == 1) med_end   = median5(xs[LROW-5], xs[LROW-4], xs[LROW-3],
                                    xs[LROW-2], xs[LROW-1]);
    __syncthreads();

    if (t < HALF)           buf[t] = med_front;
    else if (t < 2 * HALF)  xs[LROW + t - HALF] = med_end;
    __syncthreads();

    // ---- trend (K=25 moving average) + residual-in-registers ----
    float resv[GRP][4];
    #pragma unroll
    for (int j = 0; j < GRP; ++j) {
        int g = 4 * (t + NTHR * j);
        // window for outputs g..g+3 covers xs[g-12 .. g+15] == buf[g .. g+27]
        float v[28];
        #pragma unroll
        for (int q = 0; q < 7; ++q) {
            float4 f = *reinterpret_cast<const float4*>(buf + g + 4 * q);
            v[4*q+0] = f.x; v[4*q+1] = f.y; v[4*q+2] = f.z; v[4*q+3] = f.w;
        }
        float s = 0.f;
        #pragma unroll
        for (int q = 0; q < KWIN; ++q) s += v[q];
        constexpr float inv = 1.0f / (float)KWIN;
        float w1 = s  - v[0] + v[25];
        float w2 = w1 - v[1] + v[26];
        float w3 = w2 - v[2] + v[27];
        float t0 = s * inv, t1 = w1 * inv, t2 = w2 * inv, t3 = w3 * inv;
        resv[j][0] = v[12] - t0;
        resv[j][1] = v[13] - t1;
        resv[j][2] = v[14] - t2;
        resv[j][3] = v[15] - t3;
        *reinterpret_cast<float4*>(out_trend + base + g) =
            make_float4(t0, t1, t2, t3);
    }
    __syncthreads();   // all window reads done before overwrite

    // ---- residual back to LDS (each thread touches only its own slots) ----
    #pragma unroll
    for (int j = 0; j < GRP; ++j) {
        int g = 4 * (t + NTHR * j);
        *reinterpret_cast<float4*>(xs + g) =
            make_float4(resv[j][0], resv[j][1], resv[j][2], resv[j][3]);
    }
    __syncthreads();

    // ---- per-phase sums: 24 phases x 10 threads ----
    // seasonal[p] = (1/342) * sum_{k=0}^{341} xpad[24k+p],
    // xpad[m] = res[m] for m<8192 else res[m-24]  (reference's 16-elem dup pad)
    if (t < 240) {
        const int p = t / 10, s0 = t % 10;
        float acc = 0.f;
        for (int k = s0; k < NOCC; k += 10) {
            int m = PERIOD * k + p;
            if (m >= LROW) m -= PERIOD;
            acc += xs[m];
        }
        part[t] = acc;
    }
    __syncthreads();
    if (t < PERIOD) {
        float s = 0.f;
        #pragma unroll
        for (int q = 0; q < 10; ++q) s += part[t * 10 + q];
        seasonal[t] = s / (float)NOCC;
    }
    __syncthreads();

    // ---- outputs: residual - seasonal, tiled seasonal ----
    #pragma unroll
    for (int j = 0; j < GRP; ++j) {
        int g = 4 * (t + NTHR * j);
        int ph = g % PERIOD;   // multiple of 4, <= 20, so ph+3 never wraps
        float s0 = seasonal[ph + 0];
        float s1 = seasonal[ph + 1];
        float s2 = seasonal[ph + 2];
        float s3 = seasonal[ph + 3];
        *reinterpret_cast<float4*>(out_seas + base + g) =
            make_float4(s0, s1, s2, s3);
        *reinterpret_cast<float4*>(out_res + base + g) =
            make_float4(resv[j][0] - s0, resv[j][1] - s1,
                        resv[j][2] - s2, resv[j][3] - s3);
    }
}

extern "C" void kernel_launch(void* const* d_in, const int* in_sizes, int n_in,
                              void* d_out, int out_size, void* d_ws, size_t ws_size,
                              hipStream_t stream) {
    const float* x = (const float*)d_in[0];
    float* out = (float*)d_out;
    const size_t n = (size_t)in_sizes[0];          // 64*128*8192
    const int rows = (int)(n / (size_t)LROW);      // 8192
    decomp_kernel<<<rows, NTHR, 0, stream>>>(x, out, out + n, out + 2 * n);
}

// Round 2
// 210.399 us; speedup vs baseline: 1.0030x; 1.0030x over previous
//
#include <hip/hip_runtime.h>

namespace {
constexpr int LROW   = 8192;
constexpr int KWIN   = 25;
constexpr int HALF   = (KWIN - 1) / 2;    // 12
constexpr int PERIOD = 24;
constexpr int NOCC   = 342;               // (L + 16) / 24 occurrences per phase
constexpr int NTHR   = 256;
constexpr int GRP    = LROW / (4 * NTHR); // 8 float4-groups per thread
}

__device__ __forceinline__ void ce(float& x, float& y) {
    float lo = fminf(x, y), hi = fmaxf(x, y);
    x = lo; y = hi;
}

// exact median of 5 via 9-CE sorting network
__device__ __forceinline__ float median5(float a, float b, float c, float d, float e) {
    ce(a, b); ce(d, e); ce(c, e); ce(c, d); ce(a, d); ce(a, c);
    ce(b, e); ce(b, d); ce(b, c);
    return c;
}

// LDS = exactly 32768 B -> 5 blocks/CU (160 KiB / 32 KiB).
// xs[0..263] is overlaid as reduction scratch AFTER the phase gather:
//   xs[0..239]   = per-(phase,subset) partial sums
//   xs[240..263] = seasonal[24]
// (residuals live in registers, so clobbering those LDS slots is safe)
__global__ __launch_bounds__(NTHR, 5) void decomp_kernel(
    const float* __restrict__ x,
    float* __restrict__ out_res,
    float* __restrict__ out_trend,
    float* __restrict__ out_seas)
{
    __shared__ __align__(16) float xs[LROW];

    const int t = threadIdx.x;
    const size_t base = (size_t)blockIdx.x * LROW;
    const float* xr = x + base;

    // ---- stage row -> LDS (float4, coalesced global, lane-consecutive LDS) ----
    #pragma unroll
    for (int j = 0; j < GRP; ++j) {
        int g = 4 * (t + NTHR * j);
        *reinterpret_cast<float4*>(xs + g) =
            *reinterpret_cast<const float4*>(xr + g);
    }
    __syncthreads();

    // ---- trend (K=25 moving average); residuals kept in registers ----
    float resv[GRP][4];
    #pragma unroll
    for (int j = 0; j < GRP; ++j) {
        int g = 4 * (t + NTHR * j);
        // window for outputs g..g+3 covers padded indices [g-12, g+15]
        float v[28];
        if (g >= HALF && g <= LROW - 16) {
            // interior: 7 aligned float4 LDS reads (g multiple of 4)
            #pragma unroll
            for (int q = 0; q < 7; ++q) {
                float4 f = *reinterpret_cast<const float4*>(xs + g - HALF + 4 * q);
                v[4*q+0] = f.x; v[4*q+1] = f.y; v[4*q+2] = f.z; v[4*q+3] = f.w;
            }
        } else {
            // edge threads only (3 at each row end): substitute median pad
            float med = (g < HALF)
                ? median5(xs[0], xs[1], xs[2], xs[3], xs[4])
                : median5(xs[LROW-5], xs[LROW-4], xs[LROW-3], xs[LROW-2], xs[LROW-1]);
            #pragma unroll
            for (int q = 0; q < 28; ++q) {
                int idx = g - HALF + q;
                v[q] = (idx < 0 || idx >= LROW) ? med : xs[idx];
            }
        }
        float s = 0.f;
        #pragma unroll
        for (int q = 0; q < KWIN; ++q) s += v[q];
        constexpr float inv = 1.0f / (float)KWIN;
        float w1 = s  - v[0] + v[25];
        float w2 = w1 - v[1] + v[26];
        float w3 = w2 - v[2] + v[27];
        float t0 = s * inv, t1 = w1 * inv, t2 = w2 * inv, t3 = w3 * inv;
        resv[j][0] = v[12] - t0;
        resv[j][1] = v[13] - t1;
        resv[j][2] = v[14] - t2;
        resv[j][3] = v[15] - t3;
        *reinterpret_cast<float4*>(out_trend + base + g) =
            make_float4(t0, t1, t2, t3);
    }
    __syncthreads();   // all window reads done before in-place overwrite

    // ---- residual -> LDS (each thread overwrites only its own slots) ----
    #pragma unroll
    for (int j = 0; j < GRP; ++j) {
        int g = 4 * (t + NTHR * j);
        *reinterpret_cast<float4*>(xs + g) =
            make_float4(resv[j][0], resv[j][1], resv[j][2], resv[j][3]);
    }
    __syncthreads();

    // ---- per-phase partial sums: 24 phases x 10 threads ----
    // seasonal[p] = (1/342) * sum_k xpad[24k+p];
    // xpad[m] = res[m] for m<8192 else res[m-24] (reference's 16-elem dup pad)
    float acc = 0.f;
    if (t < 240) {
        const int p = t / 10, s0 = t % 10;
        for (int k = s0; k < NOCC; k += 10) {
            int m = PERIOD * k + p;
            if (m >= LROW) m -= PERIOD;
            acc += xs[m];
        }
    }
    __syncthreads();   // gather reads done before scratch overlay
    if (t < 240) xs[t] = acc;
    __syncthreads();
    if (t < PERIOD) {
        float s = 0.f;
        #pragma unroll
        for (int q = 0; q < 10; ++q) s += xs[t * 10 + q];
        xs[240 + t] = s / (float)NOCC;   // seasonal[t]
    }
    __syncthreads();

    // ---- outputs: residual - seasonal, tiled seasonal ----
    #pragma unroll
    for (int j = 0; j < GRP; ++j) {
        int g = 4 * (t + NTHR * j);
        int ph = g % PERIOD;   // multiple of 4, <= 20, so ph+3 never wraps
        float4 sv = *reinterpret_cast<const float4*>(xs + 240 + ph);
        *reinterpret_cast<float4*>(out_seas + base + g) = sv;
        *reinterpret_cast<float4*>(out_res + base + g) =
            make_float4(resv[j][0] - sv.x, resv[j][1] - sv.y,
                        resv[j][2] - sv.z, resv[j][3] - sv.w);
    }
}

extern "C" void kernel_launch(void* const* d_in, const int* in_sizes, int n_in,
                              void* d_out, int out_size, void* d_ws, size_t ws_size,
                              hipStream_t stream) {
    const float* x = (const float*)d_in[0];
    float* out = (float*)d_out;
    const size_t n = (size_t)in_sizes[0];          // 64*128*8192
    const int rows = (int)(n / (size_t)LROW);      // 8192
    decomp_kernel<<<rows, NTHR, 0, stream>>>(x, out, out + n, out + 2 * n);
}